// Round 5
// baseline (282.479 us; speedup 1.0000x reference)
//
#include <hip/hip_runtime.h>

#define N_DIM 512
#define M_DIM 512
#define NPAIR 256
#define TSTEPS 319          // 256 pairs + 63 lane skew
#define DEPTH 8             // LDS ring depth (row-pairs), power of 2
#define SLOT_BYTES 4096     // 4 chunks x (64 lanes x 16B)
#define RING_BYTES (DEPTH * SLOT_BYTES)

#define AS1 __attribute__((address_space(1)))
#define AS3 __attribute__((address_space(3)))

// Soft-DTW forward DP, exp-domain banded wavefront. One wave per batch.
// Lane l owns columns [8l, 8l+8); step s computes row-pair t = s-l.
// D is staged through an LDS ring by global_load_lds (no dest VGPRs -> the
// compiler can't sink or spill the prefetch); drained with counted vmcnt,
// never vmcnt(0). ds_read latency hides under the FMA-chain compute.
__global__ __launch_bounds__(64, 1) void softdtw_kernel(const float* __restrict__ D,
                                                        float* __restrict__ R) {
    const int b  = blockIdx.x;
    const int l  = threadIdx.x;      // lane 0..63
    const int c0 = l << 3;

    const float* __restrict__ Db = D + (size_t)b * N_DIM * M_DIM;
    float*       __restrict__ Rb = R + (size_t)b * N_DIM * M_DIM;

    __shared__ char ring[RING_BYTES] __attribute__((aligned(16)));
    const unsigned ring_base = (unsigned)(size_t)(AS3 char*)ring;

    // DMA one row-pair stripe for future step sigma into slot sigma % DEPTH.
    // Per-lane global addresses (lane's own skewed rows); wave-uniform LDS
    // base + lane*16 (hardware-defined layout).
    auto DMA4 = [&](int sigma) {
        const int tF = sigma - l;
        const int rA = min(max(2 * tF,     0), N_DIM - 1);
        const int rB = min(max(2 * tF + 1, 0), N_DIM - 1);
        const unsigned wo = (unsigned)(sigma & (DEPTH - 1)) * SLOT_BYTES;
        const float* gA = Db + (size_t)rA * M_DIM + c0;
        const float* gB = Db + (size_t)rB * M_DIM + c0;
        __builtin_amdgcn_global_load_lds((const AS1 void*)gA,       (AS3 void*)(ring + wo),        16, 0, 0);
        __builtin_amdgcn_global_load_lds((const AS1 void*)(gA + 4), (AS3 void*)(ring + wo + 1024), 16, 0, 0);
        __builtin_amdgcn_global_load_lds((const AS1 void*)gB,       (AS3 void*)(ring + wo + 2048), 16, 0, 0);
        __builtin_amdgcn_global_load_lds((const AS1 void*)(gB + 4), (AS3 void*)(ring + wo + 3072), 16, 0, 0);
    };

    // ---- persistent state (identical algebra to round 4) ----
    float Ep[8];
    #pragma unroll
    for (int k = 0; k < 8; ++k) Ep[k] = 0.0f;
    float F = 0.0f, G = 0.0f, fQ = 0.0f;
    float expA7 = 0.0f, expB7 = 0.0f;
    float E7hB = 0.0f, Fh = 0.0f;
    float endA[8], endB[8];

    // ---- prologue: pair 0 via direct loads; DMA sigma = 1..DEPTH-1 ----
    {
        const int t0 = -l;
        const int rA = min(max(2 * t0,     0), N_DIM - 1);
        const int rB = min(max(2 * t0 + 1, 0), N_DIM - 1);
        const float4 a0 = *(const float4*)(Db + (size_t)rA * M_DIM + c0);
        const float4 a1 = *(const float4*)(Db + (size_t)rA * M_DIM + c0 + 4);
        const float4 b0 = *(const float4*)(Db + (size_t)rB * M_DIM + c0);
        const float4 b1 = *(const float4*)(Db + (size_t)rB * M_DIM + c0 + 4);
        endA[0] = __expf(-a0.x); endA[1] = __expf(-a0.y);
        endA[2] = __expf(-a0.z); endA[3] = __expf(-a0.w);
        endA[4] = __expf(-a1.x); endA[5] = __expf(-a1.y);
        endA[6] = __expf(-a1.z); endA[7] = __expf(-a1.w);
        endB[0] = __expf(-b0.x); endB[1] = __expf(-b0.y);
        endB[2] = __expf(-b0.z); endB[3] = __expf(-b0.w);
        endB[4] = __expf(-b1.x); endB[5] = __expf(-b1.y);
        endB[6] = __expf(-b1.z); endB[7] = __expf(-b1.w);
    }
    for (int sig = 1; sig < DEPTH; ++sig) DMA4(sig);

    for (int s = 0; s < TSTEPS; ++s) {
        // (1) prefetch DMA for step s+DEPTH (slot s & 7; read slot is (s+1) & 7)
        DMA4(s + DEPTH);

        // (2) counted drain: the read slot's DMAs are >= 28 asm-ordered ops old
        asm volatile("s_waitcnt vmcnt(24)" ::: "memory");

        // (3) boundary from lane l-1 (end of step s-1)
        float E7sA = __shfl_up(expA7, 1);
        float E7sB = __shfl_up(expB7, 1);
        float Fs   = __shfl_up(F, 1);

        // (4) issue ds_read of next pair's D (completes under the compute below)
        const unsigned raddr = ring_base
                             + (unsigned)((s + 1) & (DEPTH - 1)) * SLOT_BYTES
                             + (unsigned)l * 16u;
        float4 qA0, qA1, qB0, qB1;
        asm volatile("ds_read_b128 %0, %4 offset:0\n\t"
                     "ds_read_b128 %1, %4 offset:1024\n\t"
                     "ds_read_b128 %2, %4 offset:2048\n\t"
                     "ds_read_b128 %3, %4 offset:3072"
                     : "=&v"(qA0), "=&v"(qA1), "=&v"(qB0), "=&v"(qB1)
                     : "v"(raddr));

        // (5) compute pair t = s - l (identical to round 4)
        const int t = s - l;
        const bool active = (t >= 0) && (t < NPAIR);
        if (active) {
            const int i0 = t << 1;
            float g, factor, eLeftA, eDiagA0;
            if (t == 0) {
                if (l == 0) { g = 0.0f; factor = 0.0f; eLeftA = 0.0f; eDiagA0 = 1.0f; }
                else {
                    g       = Fs - __logf(E7sA);
                    factor  = 1.0f / E7sA;
                    eLeftA  = 1.0f;
                    eDiagA0 = 0.0f;
                }
                fQ = 0.0f;
            } else {
                g       = G;
                factor  = __expf(g - Fs);
                eLeftA  = (l == 0) ? 0.0f : E7sA * factor;
                eDiagA0 = (l == 0) ? 0.0f : E7hB * __expf(g - Fh);
            }

            float QA[8];
            QA[0] = eDiagA0 + fQ * Ep[0];
            #pragma unroll
            for (int c = 1; c < 8; ++c) QA[c] = fQ * (Ep[c - 1] + Ep[c]);
            float EA[8];
            {
                float e = eLeftA;
                #pragma unroll
                for (int c = 0; c < 8; ++c) {
                    e = __builtin_fmaf(endA[c], e, endA[c] * QA[c]);
                    EA[c] = e;
                }
            }

            float eDiagB0 = (l == 0) ? 0.0f : E7sA * factor;
            float eLeftB  = (l == 0) ? 0.0f : E7sB * factor;
            float QB[8];
            QB[0] = eDiagB0 + EA[0];
            #pragma unroll
            for (int c = 1; c < 8; ++c) QB[c] = EA[c - 1] + EA[c];
            float EB[8];
            {
                float e = eLeftB;
                #pragma unroll
                for (int c = 0; c < 8; ++c) {
                    e = __builtin_fmaf(endB[c], e, endB[c] * QB[c]);
                    EB[c] = e;
                }
            }

            float outA[8], outB[8];
            #pragma unroll
            for (int c = 0; c < 8; ++c) outA[c] = g - __logf(EA[c]);
            #pragma unroll
            for (int c = 0; c < 8; ++c) outB[c] = g - __logf(EB[c]);
            float4* r0 = (float4*)(Rb + (size_t)i0 * M_DIM + c0);
            r0[0] = make_float4(outA[0], outA[1], outA[2], outA[3]);
            r0[1] = make_float4(outA[4], outA[5], outA[6], outA[7]);
            float4* r1 = (float4*)(Rb + (size_t)(i0 + 1) * M_DIM + c0);
            r1[0] = make_float4(outB[0], outB[1], outB[2], outB[3]);
            r1[1] = make_float4(outB[4], outB[5], outB[6], outB[7]);

            const float gn = outB[0];
            fQ = __expf(gn - g);
            F  = g;
            G  = gn;
            #pragma unroll
            for (int c = 0; c < 8; ++c) Ep[c] = EB[c];
            expA7 = EA[7];
            expB7 = EB[7];
        }

        // (6) history update (all lanes)
        E7hB = E7sB;
        Fh   = Fs;

        // (7) drain ds_reads, then convert to end[] for the next step
        asm volatile("s_waitcnt lgkmcnt(0)" ::: "memory");
        __builtin_amdgcn_sched_barrier(0);
        endA[0] = __expf(-qA0.x); endA[1] = __expf(-qA0.y);
        endA[2] = __expf(-qA0.z); endA[3] = __expf(-qA0.w);
        endA[4] = __expf(-qA1.x); endA[5] = __expf(-qA1.y);
        endA[6] = __expf(-qA1.z); endA[7] = __expf(-qA1.w);
        endB[0] = __expf(-qB0.x); endB[1] = __expf(-qB0.y);
        endB[2] = __expf(-qB0.z); endB[3] = __expf(-qB0.w);
        endB[4] = __expf(-qB1.x); endB[5] = __expf(-qB1.y);
        endB[6] = __expf(-qB1.z); endB[7] = __expf(-qB1.w);
    }
}

extern "C" void kernel_launch(void* const* d_in, const int* in_sizes, int n_in,
                              void* d_out, int out_size, void* d_ws, size_t ws_size,
                              hipStream_t stream) {
    const float* x = (const float*)d_in[0];
    float* out     = (float*)d_out;
    const int B    = in_sizes[0] / (N_DIM * M_DIM);
    softdtw_kernel<<<dim3(B), dim3(64), 0, stream>>>(x, out);
}